// Round 11
// baseline (121.641 us; speedup 1.0000x reference)
//
#include <hip/hip_runtime.h>

// AlphaCompositor: fragments (N,K,H,W) int32 indices (-1 = empty),
// alphas (N,K,H,W) f32, ptclds (C,P) f32 -> images (N,C,H,W) f32.
// N=4 K=8 H=W=256 C=32 P=200000.
//
// Strategy: transpose+downconvert ptclds (C,P) f32 -> (P,C) fp16 (12.8 MB),
// then block-cooperative composite (64 pixels/block, frag+alpha staged in
// LDS, 4 lanes/pixel gathering 16 B half8 each). Nontemporal hints on all
// streaming traffic (frag/alpha loads, output stores, ptclds reads) so the
// random-gather table keeps L2 to itself.

#define N_  4
#define K_  8
#define H_  256
#define W_  256
#define C_  32
#define P_  200000
#define HW_ (H_ * W_)

typedef _Float16 half8_t  __attribute__((ext_vector_type(8)));  // 16 B
typedef float    float4v  __attribute__((ext_vector_type(4)));  // 16 B (clang vec)

// ---------------------------------------------------------------------------
// Kernel 1: transpose ptclds (C,P) f32 -> (P,C) fp16.
// Tile = 64 points x 32 channels. P = 200000 = 3125 * 64 exactly.
// ---------------------------------------------------------------------------
__global__ __launch_bounds__(256) void transpose_ptclds_kernel(
    const float*  __restrict__ src,   // (C_, P_) f32
    _Float16*     __restrict__ dst)   // (P_, C_) fp16
{
    __shared__ float tile[32][65];   // +1 pad: conflict-free transpose
    const int p0 = blockIdx.x * 64;
    const int t  = threadIdx.x;

#pragma unroll
    for (int i = 0; i < 2; ++i) {
        const int e  = i * 256 + t;
        const int c  = e >> 4;          // 0..31
        const int pg = e & 15;          // 0..15 (x4 points)
        // Read-once stream: nontemporal (don't cache ptclds f32 source).
        const float4v v = __builtin_nontemporal_load(
            reinterpret_cast<const float4v*>(src + (size_t)c * P_ + p0 + pg * 4));
        tile[c][pg * 4 + 0] = v.x;
        tile[c][pg * 4 + 1] = v.y;
        tile[c][pg * 4 + 2] = v.z;
        tile[c][pg * 4 + 3] = v.w;
    }
    __syncthreads();

    const int p = t >> 2;               // 0..63 (point within tile)
    const int q = t & 3;                // 0..3  (channel octet)
    half8_t h;
#pragma unroll
    for (int j = 0; j < 8; ++j) h[j] = (_Float16)tile[q * 8 + j][p];
    // Table stores stay cached (composite re-reads them ~160x).
    *reinterpret_cast<half8_t*>(dst + (size_t)(p0 + p) * C_ + q * 8) = h;
}

// ---------------------------------------------------------------------------
// Kernel 2: block-cooperative composite. 64 pixels per 256-thread block.
// Streaming traffic is nontemporal; only table gathers allocate in L2.
// ---------------------------------------------------------------------------
template <bool TRANSPOSED>
__global__ __launch_bounds__(256) void composite_kernel(
    const int*   __restrict__ frags,   // (N,K,H,W) int32
    const float* __restrict__ alphas,  // (N,K,H,W) f32
    const void*  __restrict__ pt,      // (P,C) fp16 if TRANSPOSED else (C,P) f32
    float*       __restrict__ out)     // (N,C,H,W) f32
{
    __shared__ int   s_idx[K_][64];
    __shared__ float s_al [K_][64];

    const int t    = threadIdx.x;
    const int gid0 = blockIdx.x * 64;        // first pixel of block
    const int n    = gid0 >> 16;             // HW_ == 65536; 64 | HW_ so no straddle
    const int hw0  = gid0 & (HW_ - 1);
    const int base = n * K_ * HW_ + hw0;

    // Phase 1: cooperative staging, fully coalesced, nontemporal (read-once).
#pragma unroll
    for (int i = 0; i < 2; ++i) {
        const int e = i * 256 + t;           // 0..511
        const int k = e >> 6;                // 0..7
        const int p = e & 63;                // 0..63
        s_idx[k][p] = __builtin_nontemporal_load(frags  + base + k * HW_ + p);
        s_al [k][p] = __builtin_nontemporal_load(alphas + base + k * HW_ + p);
    }
    __syncthreads();

    const int p  = t >> 2;                   // pixel within block, 0..63
    const int og = t & 3;                    // channel octet 0..3

    // Weights: exclusive-transmittance scan over K=8. Redundant x4 across
    // the pixel's lanes; LDS reads are 4-way same-address broadcast (free).
    int   idx[K_];
    float w  [K_];
    float T = 1.0f;
#pragma unroll
    for (int k = 0; k < K_; ++k) {
        const int  ix    = s_idx[k][p];
        const bool valid = ix >= 0;
        const float a = valid ? s_al[k][p] : 0.0f;
        w[k] = a * T;
        T *= (1.0f - a);
        idx[k] = valid ? ix : 0;             // safe gather; weight is 0
    }

    float acc[8];
#pragma unroll
    for (int j = 0; j < 8; ++j) acc[j] = 0.0f;

    if (TRANSPOSED) {
        const _Float16* tp = (const _Float16*)pt;
        // All 8 independent gathers in flight before consumption (MLP=8).
        // Cached: the table is the reused working set.
        half8_t v[K_];
#pragma unroll
        for (int k = 0; k < K_; ++k) {
            v[k] = *reinterpret_cast<const half8_t*>(
                tp + (size_t)idx[k] * C_ + og * 8);
        }
#pragma unroll
        for (int k = 0; k < K_; ++k) {
            const float wk = w[k];
#pragma unroll
            for (int j = 0; j < 8; ++j) acc[j] += wk * (float)v[k][j];
        }
    } else {
        // Fallback: gather from original (C,P) f32 layout (slow but correct).
        const float* fp = (const float*)pt;
#pragma unroll
        for (int k = 0; k < K_; ++k) {
            const float wk = w[k];
#pragma unroll
            for (int j = 0; j < 8; ++j)
                acc[j] += wk * fp[(size_t)(og * 8 + j) * P_ + idx[k]];
        }
    }

    // Stores: write-once stream -> nontemporal (don't evict table lines).
    // Per instruction the wave writes 4 channel planes x 64 B contiguous.
    const size_t obase = (size_t)n * C_ * HW_ + hw0 + p;
#pragma unroll
    for (int j = 0; j < 8; ++j)
        __builtin_nontemporal_store(acc[j],
            out + obase + (size_t)(og * 8 + j) * HW_);
}

// ---------------------------------------------------------------------------
extern "C" void kernel_launch(void* const* d_in, const int* in_sizes, int n_in,
                              void* d_out, int out_size, void* d_ws, size_t ws_size,
                              hipStream_t stream)
{
    const int*   frags  = (const int*)  d_in[0];
    const float* alphas = (const float*)d_in[1];
    const float* ptclds = (const float*)d_in[2];   // (C,P) f32
    float*       out    = (float*)      d_out;     // (N,C,H,W) f32

    const size_t needed = (size_t)P_ * C_ * sizeof(_Float16);  // 12.8 MB

    const int total_px = N_ * HW_;                 // 262144
    const int cblocks  = total_px / 64;            // 4096 blocks x 256 thr

    if (ws_size >= needed) {
        _Float16* ptT = (_Float16*)d_ws;           // (P,C) fp16
        transpose_ptclds_kernel<<<P_ / 64, 256, 0, stream>>>(ptclds, ptT);
        composite_kernel<true><<<cblocks, 256, 0, stream>>>(frags, alphas, ptT, out);
    } else {
        composite_kernel<false><<<cblocks, 256, 0, stream>>>(frags, alphas, ptclds, out);
    }
}